// Round 1
// baseline (219.240 us; speedup 1.0000x reference)
//
#include <hip/hip_runtime.h>

#define HW   50176      // 224*224
#define NBLK 196        // HW / 256
#define NPAR 4576       // KAN_PARAMS_NUM

// ---------------------------------------------------------------------------
// Stage 1: w[b][n] = sum_k features[b][k] * fc_w[n][k] + fc_b[n]
// One wave per n (4 waves/block). features (8x1000 = 32KB) staged in LDS.
// ---------------------------------------------------------------------------
__global__ __launch_bounds__(256) void gemm_w(const float* __restrict__ feats,
                                              const float* __restrict__ fcw,
                                              const float* __restrict__ fcb,
                                              float* __restrict__ wout) {
    __shared__ float fl[8000];
    int tid = threadIdx.x;
    for (int idx = tid; idx < 8000; idx += 256) fl[idx] = feats[idx];
    __syncthreads();

    int wave = tid >> 6, lane = tid & 63;
    int n = blockIdx.x * 4 + wave;            // grid = 1144 -> n in [0,4576)

    float acc[8];
#pragma unroll
    for (int b = 0; b < 8; b++) acc[b] = 0.f;

    for (int k = lane; k < 1000; k += 64) {
        float wv = fcw[(size_t)n * 1000 + k];   // coalesced across lanes
#pragma unroll
        for (int b = 0; b < 8; b++) acc[b] += wv * fl[b * 1000 + k];
    }

#pragma unroll
    for (int b = 0; b < 8; b++) {
        float v = acc[b];
#pragma unroll
        for (int off = 32; off > 0; off >>= 1) v += __shfl_down(v, off, 64);
        if (lane == 0) wout[b * NPAR + n] = v + fcb[n];
    }
}

// ---------------------------------------------------------------------------
// Cubic Cox-de Boor basis, K=11, uniform grid g(j) = 0.25*j - 1.75.
// Work in scaled coordinate t = (x+1.75)*4 so (x-g(j))/h == t-j exactly.
// ---------------------------------------------------------------------------
__device__ __forceinline__ void basis11(float xv, float* bb) {
    float t = (xv + 1.75f) * 4.0f;
#pragma unroll
    for (int j = 0; j < 14; j++)
        bb[j] = (t >= (float)j && t < (float)(j + 1)) ? 1.f : 0.f;
#pragma unroll
    for (int j = 0; j < 13; j++)
        bb[j] = (t - (float)j) * bb[j] + ((float)(j + 2) - t) * bb[j + 1];
#pragma unroll
    for (int j = 0; j < 12; j++)
        bb[j] = 0.5f * ((t - (float)j) * bb[j] + ((float)(j + 3) - t) * bb[j + 1]);
#pragma unroll
    for (int j = 0; j < 11; j++)
        bb[j] = (1.0f / 3.0f) * ((t - (float)j) * bb[j] + ((float)(j + 4) - t) * bb[j + 1]);
}

// One input channel's contribution to all DO outputs.
// cw: coef block for this i (DO*11 floats), uw/rw: DO floats each.
// acc[] is only ever statically indexed -> stays in VGPRs.
template <int DO>
__device__ __forceinline__ void kan_step(float yi,
                                         const float* __restrict__ cw,
                                         const float* __restrict__ uw,
                                         const float* __restrict__ rw,
                                         float* acc) {
    float bb[14];
    basis11(yi, bb);
    float sil = yi / (1.f + __expf(-yi));     // silu
#pragma unroll
    for (int o = 0; o < DO; o++) {
        float s = 0.f;
#pragma unroll
        for (int k = 0; k < 11; k++) s += bb[k] * cw[o * 11 + k];
        acc[o] += s * uw[o] + sil * rw[o];
    }
}

// ---------------------------------------------------------------------------
// Stage 2: per-pixel KAN (3 -> 16 -> 16 -> 3).
// One thread per pixel; each block entirely within one batch so the param
// pointer is block-uniform (compiler emits s_load for all coefficients).
// Activation handoff between layers via per-thread LDS slots to keep all
// register arrays statically indexed (no scratch, no giant unroll).
// ---------------------------------------------------------------------------
__global__ __launch_bounds__(256) void kan_eval(const float* __restrict__ x,
                                                const float* __restrict__ wv,
                                                float* __restrict__ out) {
    __shared__ float h[16 * 256];
    int tid = threadIdx.x;
    int b = blockIdx.x / NBLK;
    int hw = (blockIdx.x - b * NBLK) * 256 + tid;

    const float* wp = wv + b * NPAR;                 // block-uniform
    const float* xb = x + (size_t)b * 3 * HW + hw;

    // ---- layer 1: DI=3, DO=16. PARAM_IDX: coef@0, uw@528, rw@576
    float AR[16];
#pragma unroll
    for (int o = 0; o < 16; o++) AR[o] = 0.f;
    kan_step<16>(xb[0],        wp + 0,       wp + 528,      wp + 576,      AR);
    kan_step<16>(xb[HW],       wp + 176,     wp + 528 + 16, wp + 576 + 16, AR);
    kan_step<16>(xb[2 * HW],   wp + 352,     wp + 528 + 32, wp + 576 + 32, AR);
#pragma unroll
    for (int o = 0; o < 16; o++) h[o * 256 + tid] = AR[o];

    // ---- layer 2: DI=16, DO=16. coef@624, uw@3440, rw@3696
    float BR[16];
#pragma unroll
    for (int o = 0; o < 16; o++) BR[o] = 0.f;
#pragma unroll 1
    for (int i = 0; i < 16; i++) {
        float yi = h[i * 256 + tid];
        kan_step<16>(yi, wp + 624 + i * 176, wp + 3440 + i * 16, wp + 3696 + i * 16, BR);
    }
#pragma unroll
    for (int o = 0; o < 16; o++) h[o * 256 + tid] = BR[o];

    // ---- layer 3: DI=16, DO=3. coef@3952, uw@4480, rw@4528
    float CR[3] = {0.f, 0.f, 0.f};
#pragma unroll 1
    for (int i = 0; i < 16; i++) {
        float yi = h[i * 256 + tid];
        kan_step<3>(yi, wp + 3952 + i * 33, wp + 4480 + i * 3, wp + 4528 + i * 3, CR);
    }

    float* ob = out + (size_t)b * 3 * HW + hw;
    ob[0]      = CR[0];
    ob[HW]     = CR[1];
    ob[2 * HW] = CR[2];
}

// ---------------------------------------------------------------------------
extern "C" void kernel_launch(void* const* d_in, const int* in_sizes, int n_in,
                              void* d_out, int out_size, void* d_ws, size_t ws_size,
                              hipStream_t stream) {
    const float* x     = (const float*)d_in[0];   // (8,3,224,224)
    const float* feats = (const float*)d_in[1];   // (8,1000)
    const float* fcw   = (const float*)d_in[2];   // (4576,1000)
    const float* fcb   = (const float*)d_in[3];   // (4576,)
    float* outp = (float*)d_out;                  // (8,3,224,224)
    float* wbuf = (float*)d_ws;                   // 8*4576 floats = 146 KB

    hipLaunchKernelGGL(gemm_w, dim3(NPAR / 4), dim3(256), 0, stream,
                       feats, fcw, fcb, wbuf);
    hipLaunchKernelGGL(kan_eval, dim3(8 * NBLK), dim3(256), 0, stream,
                       x, wbuf, outp);
}

// Round 2
// 179.453 us; speedup vs baseline: 1.2217x; 1.2217x over previous
//
#include <hip/hip_runtime.h>

#define HW   50176      // 224*224
#define NBLK 196        // HW / 256
#define NPAR 4576       // KAN_PARAMS_NUM

// ---------------------------------------------------------------------------
// Stage 1: w[b][n] = sum_k features[b][k] * fc_w[n][k] + fc_b[n]
// 286 blocks; each stages features (8x1000=32KB) to LDS once, then handles
// 16 n-values (4 per wave). float4 global reads, ds_read_b128 LDS reads.
// ---------------------------------------------------------------------------
__global__ __launch_bounds__(256) void gemm_w(const float* __restrict__ feats,
                                              const float* __restrict__ fcw,
                                              const float* __restrict__ fcb,
                                              float* __restrict__ wout) {
    __shared__ float fl[8000];
    int tid = threadIdx.x;
    const float4* f4 = (const float4*)feats;
    float4* fl4 = (float4*)fl;
    for (int idx = tid; idx < 2000; idx += 256) fl4[idx] = f4[idx];
    __syncthreads();

    int wave = tid >> 6, lane = tid & 63;
    int gw = blockIdx.x * 4 + wave;          // 0..1143

#pragma unroll 1
    for (int rep = 0; rep < 4; rep++) {
        int n = gw * 4 + rep;                // 0..4575
        const float4* wrow = (const float4*)(fcw + (size_t)n * 1000);

        float acc[8];
#pragma unroll
        for (int b = 0; b < 8; b++) acc[b] = 0.f;

        // 1000 floats = 250 float4; lanes cover 64 float4 per sweep
#pragma unroll 1
        for (int m = 0; m < 4; m++) {
            int q = m * 64 + lane;           // float4 index
            if (q < 250) {
                float4 wv = wrow[q];
#pragma unroll
                for (int b = 0; b < 8; b++) {
                    float4 fv = fl4[b * 250 + q];
                    acc[b] += wv.x * fv.x + wv.y * fv.y + wv.z * fv.z + wv.w * fv.w;
                }
            }
        }

#pragma unroll
        for (int b = 0; b < 8; b++) {
            float v = acc[b];
#pragma unroll
            for (int off = 32; off > 0; off >>= 1) v += __shfl_down(v, off, 64);
            if (lane == 0) wout[b * NPAR + n] = v + fcb[n];
        }
    }
}

// ---------------------------------------------------------------------------
// Stage 1.5: in-place coef *= uw (per (b,layer,i,o,k)). Race-free: coef slots
// written once each, uw slots only read.
// ---------------------------------------------------------------------------
__global__ __launch_bounds__(256) void premult(float* __restrict__ w) {
    int j = blockIdx.x * 256 + threadIdx.x;
    if (j >= 8 * 3872) return;
    int b = j / 3872, c = j - b * 3872;
    int base, uwbase, DO, cc;
    if (c < 528)       { cc = c;        base = 0;    uwbase = 528;  DO = 16; }
    else if (c < 3344) { cc = c - 528;  base = 624;  uwbase = 3440; DO = 16; }
    else               { cc = c - 3344; base = 3952; uwbase = 4480; DO = 3;  }
    int oi = cc / 11;              // i*DO + o
    float* wb = w + b * NPAR;
    wb[base + cc] *= wb[uwbase + oi];
}

// ---------------------------------------------------------------------------
// Closed-form cardinal cubic basis: at t=(x+1.75)*4, only taps
// k = jt-3..jt (jt=floor(t)) are nonzero, with the standard uniform-knot
// cubic polynomials in u = t - jt. Scatter into dense 11-vector, then dense
// dot with block-uniform (s_load) coefficients.
// cw: premultiplied coef (DO*11), rw: DO floats. acc statically indexed.
// ---------------------------------------------------------------------------
template <int DO, int K0>
__device__ __forceinline__ void kan_step(float yi,
                                         const float* __restrict__ cw,
                                         const float* __restrict__ rw,
                                         float* acc) {
    float t  = (yi + 1.75f) * 4.0f;
    float ft = floorf(t);
    ft = fminf(fmaxf(ft, 0.f), 13.f);
    float u  = t - ft;
    float u2 = u * u, u3 = u2 * u;
    float omu = 1.f - u;
    float b0 = (1.f / 6.f) * omu * omu * omu;
    float b3 = (1.f / 6.f) * u3;
    float b1 = 0.5f * u3 - u2 + (2.f / 3.f);
    float b2 = 1.f - b0 - b1 - b3;
    int jt = (int)ft;
    // out-of-domain -> no tap matches -> all-zero basis (matches reference)
    if (!(t >= 0.f && t < 14.f)) jt = 99;

    float bb[11];
#pragma unroll
    for (int k = K0; k < 11; k++) {
        float v = (jt == k + 3) ? b0 : 0.f;
        v = (jt == k + 2) ? b1 : v;
        v = (jt == k + 1) ? b2 : v;
        v = (jt == k)     ? b3 : v;
        bb[k] = v;
    }

    float sil = yi / (1.f + __expf(-yi));
#pragma unroll
    for (int o = 0; o < DO; o++) {
#pragma unroll
        for (int k = K0; k < 11; k++) acc[o] = fmaf(bb[k], cw[o * 11 + k], acc[o]);
        acc[o] = fmaf(sil, rw[o], acc[o]);
    }
}

// ---------------------------------------------------------------------------
// Stage 2: per-pixel KAN (3 -> 16 -> 16 -> 3). One thread per pixel; block
// entirely within one batch so all param access is block-uniform (s_load).
// Layer-to-layer activations via per-thread LDS slots (keeps register arrays
// statically indexed). Layer 1 uses taps k=4..10 only (x in [0,1)).
// ---------------------------------------------------------------------------
__global__ __launch_bounds__(256) void kan_eval(const float* __restrict__ x,
                                                const float* __restrict__ wv,
                                                float* __restrict__ out) {
    __shared__ float h[16 * 256];
    int tid = threadIdx.x;
    int b = blockIdx.x / NBLK;
    int hw = (blockIdx.x - b * NBLK) * 256 + tid;

    const float* wp = wv + b * NPAR;                 // block-uniform
    const float* xb = x + (size_t)b * 3 * HW + hw;

    // ---- layer 1: DI=3, DO=16. coef@0 (premult), rw@576
    float AR[16];
#pragma unroll
    for (int o = 0; o < 16; o++) AR[o] = 0.f;
    kan_step<16, 4>(xb[0],      wp + 0,   wp + 576,      AR);
    kan_step<16, 4>(xb[HW],     wp + 176, wp + 576 + 16, AR);
    kan_step<16, 4>(xb[2 * HW], wp + 352, wp + 576 + 32, AR);
#pragma unroll
    for (int o = 0; o < 16; o++) h[o * 256 + tid] = AR[o];

    // ---- layer 2: DI=16, DO=16. coef@624 (premult), rw@3696
    float BR[16];
#pragma unroll
    for (int o = 0; o < 16; o++) BR[o] = 0.f;
#pragma unroll 1
    for (int i = 0; i < 16; i++) {
        float yi = h[i * 256 + tid];
        kan_step<16, 0>(yi, wp + 624 + i * 176, wp + 3696 + i * 16, BR);
    }
#pragma unroll
    for (int o = 0; o < 16; o++) h[o * 256 + tid] = BR[o];

    // ---- layer 3: DI=16, DO=3. coef@3952 (premult), rw@4528
    float CR[3] = {0.f, 0.f, 0.f};
#pragma unroll 1
    for (int i = 0; i < 16; i++) {
        float yi = h[i * 256 + tid];
        kan_step<3, 0>(yi, wp + 3952 + i * 33, wp + 4528 + i * 3, CR);
    }

    float* ob = out + (size_t)b * 3 * HW + hw;
    ob[0]      = CR[0];
    ob[HW]     = CR[1];
    ob[2 * HW] = CR[2];
}

// ---------------------------------------------------------------------------
extern "C" void kernel_launch(void* const* d_in, const int* in_sizes, int n_in,
                              void* d_out, int out_size, void* d_ws, size_t ws_size,
                              hipStream_t stream) {
    const float* x     = (const float*)d_in[0];   // (8,3,224,224)
    const float* feats = (const float*)d_in[1];   // (8,1000)
    const float* fcw   = (const float*)d_in[2];   // (4576,1000)
    const float* fcb   = (const float*)d_in[3];   // (4576,)
    float* outp = (float*)d_out;                  // (8,3,224,224)
    float* wbuf = (float*)d_ws;                   // 8*4576 floats = 146 KB

    hipLaunchKernelGGL(gemm_w, dim3(286), dim3(256), 0, stream,
                       feats, fcw, fcb, wbuf);
    hipLaunchKernelGGL(premult, dim3((8 * 3872 + 255) / 256), dim3(256), 0, stream,
                       wbuf);
    hipLaunchKernelGGL(kan_eval, dim3(8 * NBLK), dim3(256), 0, stream,
                       x, wbuf, outp);
}